// Round 10
// baseline (666.587 us; speedup 1.0000x reference)
//
#include <hip/hip_runtime.h>
#include <math.h>

#define BB 8
#define NN 2000
#define FIN 128
#define HH 4
#define FO 64
#define CC 256  // HH*FO

typedef short bf16x8 __attribute__((ext_vector_type(8)));
typedef float f32x4 __attribute__((ext_vector_type(4)));
typedef unsigned long long u64;

__device__ __forceinline__ unsigned short f2bf(float v) {
    union { float f; unsigned u; } x;
    x.f = v;
    unsigned r = x.u + 0x7fffu + ((x.u >> 16) & 1u);  // RNE
    return (unsigned short)(r >> 16);
}

// ---------------------------------------------------------------------------
// K1 (ALL-IN-ONE front end):
//   blocks [0,1000):    h = x@W -> e_src/e_dst (shuffle reduce) + hT
//                       (MFMA-fragment order) via 8KB LDS restage.
//   blocks [1000,2000): adjacency bitmask (grid-stride, 16 ballots/wave).
//   blocks [2000,2048): zero hT's j-pad (j in [2000,2048)) -- pad must be
//                       FINITE (MFMA 0*NaN would poison acc).
// ---------------------------------------------------------------------------
__global__ __launch_bounds__(256) void k_gemm_all(const float* __restrict__ x,
                                                  const float* __restrict__ W,
                                                  const float* __restrict__ a,
                                                  const int* __restrict__ adj,
                                                  float* __restrict__ e_src,
                                                  float* __restrict__ e_dst,
                                                  unsigned short* __restrict__ hT,
                                                  u64* __restrict__ adjb) {
    const int t = threadIdx.x;
    if (blockIdx.x >= 1000) {
        const int bx = blockIdx.x - 1000;
        if (bx < 1000) {
            const int lane = t & 63;
            for (int w = bx * 4 + (t >> 6); w < 64000; w += 4000) {
                const int i = w >> 5, wd = w & 31;
                const int j = wd * 64 + lane;
                int av = 0;
                if (j < NN) av = adj[(size_t)i * NN + j];
                const u64 mask = __ballot(av != 0);
                if (lane == 0) adjb[(size_t)i * 32 + wd] = mask;
            }
        } else {
            const int k = (bx - 1000) * 256 + t;  // [0, 12288)
            const int bh = k / 384;
            const int r = k - bh * 384;
            const int ft = r / 96;
            const int c = r - ft * 96;
            size_t off;
            if (c < 32) off = 62 * 2048 + ft * 512 + 256 + c * 8;
            else        off = 63 * 2048 + ft * 512 + (size_t)(c - 32) * 8;
            uint4 z; z.x = 0; z.y = 0; z.z = 0; z.w = 0;
            *(uint4*)(hT + (size_t)bh * 131072 + off) = z;
        }
        return;
    }
    __shared__ __align__(16) char smraw[8192];
    float* xs = (float*)smraw;                    // [16][128] during compute
    unsigned short* sm = (unsigned short*)smraw;  // [16][256] after re-barrier
    const int row0 = blockIdx.x * 16;
    for (int k = t; k < 16 * FIN; k += 256) xs[k] = x[row0 * FIN + k];
    __syncthreads();
    const int c = t;
    const int h = c >> 6, f = c & 63, lane = t & 63;
    float acc[16];
#pragma unroll
    for (int r = 0; r < 16; ++r) acc[r] = 0.f;
#pragma unroll 2
    for (int k = 0; k < FIN; k += 4) {
        const float w0 = W[(k + 0) * CC + c];
        const float w1 = W[(k + 1) * CC + c];
        const float w2 = W[(k + 2) * CC + c];
        const float w3 = W[(k + 3) * CC + c];
#pragma unroll
        for (int r = 0; r < 16; ++r) {
            const float4 xv = *(const float4*)(xs + r * FIN + k);
            acc[r] = fmaf(xv.x, w0, fmaf(xv.y, w1, fmaf(xv.z, w2, fmaf(xv.w, w3, acc[r]))));
        }
    }
    const int b = row0 / NN;
    const int n0 = row0 - b * NN;
    const float aS = a[h * 2 * FO + f];
    const float aD = a[h * 2 * FO + FO + f];
#pragma unroll
    for (int r = 0; r < 16; ++r) {
        float p1 = acc[r] * aS;
        float p2 = acc[r] * aD;
#pragma unroll
        for (int off = 32; off > 0; off >>= 1) {
            p1 += __shfl_xor(p1, off);
            p2 += __shfl_xor(p2, off);
        }
        if (lane == 0) {
            e_src[(b * HH + h) * NN + n0 + r] = p1;
            e_dst[(b * HH + h) * NN + n0 + r] = p2;
        }
    }
    __syncthreads();  // everyone done reading xs
#pragma unroll
    for (int r = 0; r < 16; ++r) sm[r * 256 + c] = f2bf(acc[r]);
    __syncthreads();
    const int s = n0 >> 5;
    const int qbase = (n0 >> 3) & 3;  // 0 or 2
    unsigned short* base = hT + (size_t)b * HH * 131072 + s * 2048;
#pragma unroll
    for (int it2 = 0; it2 < 2; ++it2) {
        const int k2 = it2 * 256 + t;
        const int hh = (k2 >> 7) & 3, ft2 = (k2 >> 5) & 3, l16 = (k2 >> 1) & 15, g = k2 & 1;
        const int col = hh * 64 + ft2 * 16 + l16;
        unsigned v[4];
#pragma unroll
        for (int p = 0; p < 4; ++p) {
            const unsigned lo = sm[(g * 8 + 2 * p) * 256 + col];
            const unsigned hi = sm[(g * 8 + 2 * p + 1) * 256 + col];
            v[p] = lo | (hi << 16);
        }
        uint4 pkt; pkt.x = v[0]; pkt.y = v[1]; pkt.z = v[2]; pkt.w = v[3];
        *(uint4*)(base + (size_t)hh * 131072 + ft2 * 512 + (qbase + g) * 128 + l16 * 8) = pkt;
    }
}

// ---------------------------------------------------------------------------
// K2: MFMA out kernel with FUSED softmax AND FUSED alpha write.
// XCD-swizzled (b = blk&7).  Phase A: psum-only pass -> rl (+rlArr for tail).
// Phase B: q = exp(s)*rl -> bf16 MFMA (pre-normalized acc) + q staged in a
// double-buffered LDS tile ps[2][16 i][4 h][68 jl] and streamed to alpha as
// dense 256B-per-row float4 stores (1 barrier per jt).
// jt=31 store is CLAMPED to j < NN (R9 bug: unclamped pad writes overran
// each row by 192 floats, zeroing the next row's j<48 -- absmax 1.7e-2).
// RACE SAFETY: hT+adjb scratch occupy alpha rows b=0,i<280 -> blocks
// (b==0, it<18) skip alpha stores; k_alpha_tail fills rows [0,288) after.
// ---------------------------------------------------------------------------
__global__ __launch_bounds__(256) void k_out_mfma6(const u64* __restrict__ adjb,
                                                   const unsigned short* __restrict__ hT,
                                                   const float* __restrict__ e_src,
                                                   const float* __restrict__ e_dst,
                                                   float* __restrict__ rlArr,
                                                   float* __restrict__ out,
                                                   float* __restrict__ alpha) {
    __shared__ __align__(16) float ps[2][16][HH][68];  // 34.8 KB
    const int blk = blockIdx.x;  // [0, 1000)
    const int b = blk & 7;       // XCD-aligned (1000 = 8 x 125)
    const int it = blk >> 3;
    const int i0 = it * 16;
    const int t = threadIdx.x;
    const int h = t >> 6, lane = t & 63;
    const int l16 = lane & 15, quad = lane >> 4;
    const int i = i0 + l16;  // < 2000 always
    const int bh = b * HH + h;
    const float es = e_src[bh * NN + i];
    const float* ed = e_dst + bh * NN;
    const u64* ab = adjb + (size_t)i * 32;
    const unsigned short* hbase = hT + (size_t)bh * 131072 + (size_t)lane * 8;

    // ---- Phase A: denominator (pad bits mask the j>=2000 overread) ----
    float psum = 0.f;
#pragma unroll 2
    for (int jt = 0; jt < 32; ++jt) {
        const u64 bits = ab[jt];
        const unsigned m0 = ((unsigned)(bits >> (quad * 8))) & 0xffu;
        const unsigned m1 = ((unsigned)(bits >> 32) >> (quad * 8)) & 0xffu;
        const float* ep = ed + jt * 64 + quad * 8;
        const float4 ea0 = *(const float4*)(ep);
        const float4 ea1 = *(const float4*)(ep + 4);
        const float4 eb0 = *(const float4*)(ep + 32);
        const float4 eb1 = *(const float4*)(ep + 36);
        const float ev0[8] = {ea0.x, ea0.y, ea0.z, ea0.w, ea1.x, ea1.y, ea1.z, ea1.w};
        const float ev1[8] = {eb0.x, eb0.y, eb0.z, eb0.w, eb1.x, eb1.y, eb1.z, eb1.w};
#pragma unroll
        for (int e = 0; e < 8; ++e) {
            float s0 = es + ev0[e]; s0 = s0 > 0.f ? s0 : 0.2f * s0;
            float s1 = es + ev1[e]; s1 = s1 > 0.f ? s1 : 0.2f * s1;
            psum += ((m0 >> e) & 1u) ? __expf(s0) : 0.f;
            psum += ((m1 >> e) & 1u) ? __expf(s1) : 0.f;
        }
    }
    psum += __shfl_xor(psum, 16);
    psum += __shfl_xor(psum, 32);
    const float rl = 1.f / psum;
    if (quad == 0) rlArr[bh * NN + i] = rl;

    // ---- Phase B: MFMA + alpha stream ----
    f32x4 acc[4];
#pragma unroll
    for (int ft = 0; ft < 4; ++ft) {
        acc[ft][0] = 0.f; acc[ft][1] = 0.f; acc[ft][2] = 0.f; acc[ft][3] = 0.f;
    }
    const bool wr = (b > 0) || (it >= 18);   // skip rows overlapping hT/adjb scratch
    const int ii = t >> 4, g = t & 15;
    float* arowbase = alpha + ((size_t)b * NN + i0 + ii) * (NN * HH);
    int buf = 0;
    for (int jt = 0; jt < 32; ++jt) {
        const u64 bits = ab[jt];
        const unsigned m0 = ((unsigned)(bits >> (quad * 8))) & 0xffu;
        const unsigned m1 = ((unsigned)(bits >> 32) >> (quad * 8)) & 0xffu;
        const float* ep = ed + jt * 64 + quad * 8;
        const float4 ea0 = *(const float4*)(ep);
        const float4 ea1 = *(const float4*)(ep + 4);
        const float4 eb0 = *(const float4*)(ep + 32);
        const float4 eb1 = *(const float4*)(ep + 36);
        const float ev0[8] = {ea0.x, ea0.y, ea0.z, ea0.w, ea1.x, ea1.y, ea1.z, ea1.w};
        const float ev1[8] = {eb0.x, eb0.y, eb0.z, eb0.w, eb1.x, eb1.y, eb1.z, eb1.w};
        const unsigned short* hp0 = hbase + (size_t)jt * 4096;
        {   // kk = 0
            f32x4 q0, q1;
            bf16x8 bfr;
#pragma unroll
            for (int e = 0; e < 8; ++e) {
                float s = es + ev0[e];
                s = s > 0.f ? s : 0.2f * s;
                const float q = (((m0 >> e) & 1u) ? __expf(s) : 0.f) * rl;
                bfr[e] = (short)f2bf(q);
                if (e < 4) q0[e] = q; else q1[e - 4] = q;
            }
            *(f32x4*)(&ps[buf][l16][h][quad * 8]) = q0;
            *(f32x4*)(&ps[buf][l16][h][quad * 8 + 4]) = q1;
#pragma unroll
            for (int ft = 0; ft < 4; ++ft) {
                const bf16x8 af = *(const bf16x8*)(hp0 + ft * 512);
                acc[ft] = __builtin_amdgcn_mfma_f32_16x16x32_bf16(af, bfr, acc[ft], 0, 0, 0);
            }
        }
        {   // kk = 1
            f32x4 q0, q1;
            bf16x8 bfr;
#pragma unroll
            for (int e = 0; e < 8; ++e) {
                float s = es + ev1[e];
                s = s > 0.f ? s : 0.2f * s;
                const float q = (((m1 >> e) & 1u) ? __expf(s) : 0.f) * rl;
                bfr[e] = (short)f2bf(q);
                if (e < 4) q0[e] = q; else q1[e - 4] = q;
            }
            *(f32x4*)(&ps[buf][l16][h][32 + quad * 8]) = q0;
            *(f32x4*)(&ps[buf][l16][h][32 + quad * 8 + 4]) = q1;
#pragma unroll
            for (int ft = 0; ft < 4; ++ft) {
                const bf16x8 af = *(const bf16x8*)(hp0 + 2048 + ft * 512);
                acc[ft] = __builtin_amdgcn_mfma_f32_16x16x32_bf16(af, bfr, acc[ft], 0, 0, 0);
            }
        }
        __syncthreads();  // ps[buf] complete for all 4 heads
        if (wr) {
            float* arow = arowbase + (size_t)jt * 256;
            const int jlim = NN - jt * 64;  // 64 except jt=31 -> 16 (row end!)
#pragma unroll
            for (int c = 0; c < 4; ++c) {
                const int jl = c * 16 + g;        // lanes g -> contiguous 256B
                if (jl < jlim) {
                    float4 ov;
                    ov.x = ps[buf][ii][0][jl];
                    ov.y = ps[buf][ii][1][jl];
                    ov.z = ps[buf][ii][2][jl];
                    ov.w = ps[buf][ii][3][jl];
                    *(float4*)(arow + (size_t)jl * 4) = ov;
                }
            }
        }
        buf ^= 1;  // next jt writes the other buffer; this one is rewritten
                   // only after the NEXT barrier, by which its reads are done
    }
    // ---- out epilogue: cross-head reduction (acc already normalized) ----
    __syncthreads();
    float* red = (float*)ps;  // [16][68]
#pragma unroll
    for (int ph = 0; ph < HH; ++ph) {
        if (h == ph) {
            if (ph == 0) {
#pragma unroll
                for (int ft = 0; ft < 4; ++ft)
                    *(f32x4*)(&red[l16 * 68 + ft * 16 + quad * 4]) = acc[ft];
            } else {
#pragma unroll
                for (int ft = 0; ft < 4; ++ft) {
                    f32x4 cur = *(const f32x4*)(&red[l16 * 68 + ft * 16 + quad * 4]);
#pragma unroll
                    for (int r = 0; r < 4; ++r) cur[r] += acc[ft][r];
                    *(f32x4*)(&red[l16 * 68 + ft * 16 + quad * 4]) = cur;
                }
            }
        }
        __syncthreads();
    }
    const int f4 = (t & 15) * 4;
    const f32x4 v = *(const f32x4*)(&red[(t >> 4) * 68 + f4]);
    f32x4 o;
#pragma unroll
    for (int r = 0; r < 4; ++r) o[r] = 0.25f * v[r];
    *(f32x4*)(out + (size_t)(b * NN + i0 + (t >> 4)) * FO + f4) = o;
}

// ---------------------------------------------------------------------------
// K3 (LAST): alpha tail for b=0, i in [0,288) -- the rows whose alpha region
// held hT/adjb scratch.  Reads the ORIGINAL adj input (never overwritten;
// avoids R1's scratch-read race).  Runs after mfma6, so hT is dead.
// ---------------------------------------------------------------------------
__global__ __launch_bounds__(256) void k_alpha_tail(const int* __restrict__ adj,
                                                    const float* __restrict__ e_src,
                                                    const float* __restrict__ e_dst,
                                                    const float* __restrict__ rlArr,
                                                    float* __restrict__ alpha) {
    const int i = blockIdx.x;  // [0, 288), b = 0
    const int t = threadIdx.x;
    float ei[HH], rr[HH];
#pragma unroll
    for (int h = 0; h < HH; ++h) {
        ei[h] = e_src[h * NN + i];
        rr[h] = rlArr[h * NN + i];
    }
    const int* adjrow = adj + (size_t)i * NN;
    float* arow = alpha + (size_t)i * (NN * HH);
#pragma unroll
    for (int k = 0; k < 8; ++k) {
        const int j = k * 256 + t;
        if (j < NN) {
            const bool av = adjrow[j] != 0;
            float o[HH];
#pragma unroll
            for (int h = 0; h < HH; ++h) {
                float s = ei[h] + e_dst[h * NN + j];
                s = s > 0.f ? s : 0.2f * s;
                o[h] = av ? __expf(s) * rr[h] : 0.f;
            }
            float4 ov = {o[0], o[1], o[2], o[3]};
            *(float4*)(arow + (size_t)j * HH) = ov;
        }
    }
}

// ---------------------------------------------------------------------------
// Launch (3 kernels).  hT at the start of the alpha output region; mfma6
// writes alpha only for rows >= 288 (b=0) -- disjoint from hT/adjb scratch,
// so concurrent read/write is safe; tail fills [0,288) afterwards.
//   ws bytes: [0,256000) e_src | [256000,512000) e_dst | [512000,768000) rl
//             [768000,1280000) adjb (if ws_size >= 1280000)
// ---------------------------------------------------------------------------
extern "C" void kernel_launch(void* const* d_in, const int* in_sizes, int n_in,
                              void* d_out, int out_size, void* d_ws, size_t ws_size,
                              hipStream_t stream) {
    const float* x  = (const float*)d_in[0];
    const int* adj  = (const int*)d_in[1];
    const float* W  = (const float*)d_in[2];
    const float* a  = (const float*)d_in[3];

    float* out = (float*)d_out;                         // B*N*FO floats
    float* alpha = out + (size_t)BB * NN * FO;          // B*N*N*H floats

    unsigned short* hT = (unsigned short*)alpha;        // 8.39 MB scratch (rows < 263)
    u64* adjb_scratch = (u64*)((char*)alpha + 8388608); // rows 262..279

    char* ws = (char*)d_ws;
    float* e_src = (float*)ws;
    float* e_dst = (float*)(ws + 256000);
    float* rlArr = (float*)(ws + 512000);
    const bool ws_has_adjb = ws_size >= 1280000;
    u64* adjb = ws_has_adjb ? (u64*)(ws + 768000) : adjb_scratch;

    k_gemm_all<<<2048, 256, 0, stream>>>(x, W, a, adj, e_src, e_dst, hT, adjb);
    k_out_mfma6<<<1000, 256, 0, stream>>>(adjb, hT, e_src, e_dst, rlArr, out, alpha);
    k_alpha_tail<<<288, 256, 0, stream>>>(adj, e_src, e_dst, rlArr, alpha);
}

// Round 11
// 658.634 us; speedup vs baseline: 1.0121x; 1.0121x over previous
//
#include <hip/hip_runtime.h>
#include <math.h>

#define BB 8
#define NN 2000
#define FIN 128
#define HH 4
#define FO 64
#define CC 256  // HH*FO

typedef short bf16x8 __attribute__((ext_vector_type(8)));
typedef float f32x4 __attribute__((ext_vector_type(4)));
typedef unsigned long long u64;

__device__ __forceinline__ unsigned short f2bf(float v) {
    union { float f; unsigned u; } x;
    x.f = v;
    unsigned r = x.u + 0x7fffu + ((x.u >> 16) & 1u);  // RNE
    return (unsigned short)(r >> 16);
}

// ---------------------------------------------------------------------------
// K1 (ALL-IN-ONE front end):
//   blocks [0,1000):    h = x@W -> e_src/e_dst (shuffle reduce) + hT
//                       (MFMA-fragment order) via 8KB LDS restage.
//   blocks [1000,2000): adjacency bitmask (grid-stride, 16 ballots/wave).
//   blocks [2000,2048): zero hT's j-pad (j in [2000,2048)) -- pad must be
//                       FINITE (MFMA 0*NaN would poison acc).
// ---------------------------------------------------------------------------
__global__ __launch_bounds__(256) void k_gemm_all(const float* __restrict__ x,
                                                  const float* __restrict__ W,
                                                  const float* __restrict__ a,
                                                  const int* __restrict__ adj,
                                                  float* __restrict__ e_src,
                                                  float* __restrict__ e_dst,
                                                  unsigned short* __restrict__ hT,
                                                  u64* __restrict__ adjb) {
    const int t = threadIdx.x;
    if (blockIdx.x >= 1000) {
        const int bx = blockIdx.x - 1000;
        if (bx < 1000) {
            const int lane = t & 63;
            for (int w = bx * 4 + (t >> 6); w < 64000; w += 4000) {
                const int i = w >> 5, wd = w & 31;
                const int j = wd * 64 + lane;
                int av = 0;
                if (j < NN) av = adj[(size_t)i * NN + j];
                const u64 mask = __ballot(av != 0);
                if (lane == 0) adjb[(size_t)i * 32 + wd] = mask;
            }
        } else {
            const int k = (bx - 1000) * 256 + t;  // [0, 12288)
            const int bh = k / 384;
            const int r = k - bh * 384;
            const int ft = r / 96;
            const int c = r - ft * 96;
            size_t off;
            if (c < 32) off = 62 * 2048 + ft * 512 + 256 + c * 8;
            else        off = 63 * 2048 + ft * 512 + (size_t)(c - 32) * 8;
            uint4 z; z.x = 0; z.y = 0; z.z = 0; z.w = 0;
            *(uint4*)(hT + (size_t)bh * 131072 + off) = z;
        }
        return;
    }
    __shared__ __align__(16) char smraw[8192];
    float* xs = (float*)smraw;                    // [16][128] during compute
    unsigned short* sm = (unsigned short*)smraw;  // [16][256] after re-barrier
    const int row0 = blockIdx.x * 16;
    for (int k = t; k < 16 * FIN; k += 256) xs[k] = x[row0 * FIN + k];
    __syncthreads();
    const int c = t;
    const int h = c >> 6, f = c & 63, lane = t & 63;
    float acc[16];
#pragma unroll
    for (int r = 0; r < 16; ++r) acc[r] = 0.f;
#pragma unroll 2
    for (int k = 0; k < FIN; k += 4) {
        const float w0 = W[(k + 0) * CC + c];
        const float w1 = W[(k + 1) * CC + c];
        const float w2 = W[(k + 2) * CC + c];
        const float w3 = W[(k + 3) * CC + c];
#pragma unroll
        for (int r = 0; r < 16; ++r) {
            const float4 xv = *(const float4*)(xs + r * FIN + k);
            acc[r] = fmaf(xv.x, w0, fmaf(xv.y, w1, fmaf(xv.z, w2, fmaf(xv.w, w3, acc[r]))));
        }
    }
    const int b = row0 / NN;
    const int n0 = row0 - b * NN;
    const float aS = a[h * 2 * FO + f];
    const float aD = a[h * 2 * FO + FO + f];
#pragma unroll
    for (int r = 0; r < 16; ++r) {
        float p1 = acc[r] * aS;
        float p2 = acc[r] * aD;
#pragma unroll
        for (int off = 32; off > 0; off >>= 1) {
            p1 += __shfl_xor(p1, off);
            p2 += __shfl_xor(p2, off);
        }
        if (lane == 0) {
            e_src[(b * HH + h) * NN + n0 + r] = p1;
            e_dst[(b * HH + h) * NN + n0 + r] = p2;
        }
    }
    __syncthreads();  // everyone done reading xs
#pragma unroll
    for (int r = 0; r < 16; ++r) sm[r * 256 + c] = f2bf(acc[r]);
    __syncthreads();
    const int s = n0 >> 5;
    const int qbase = (n0 >> 3) & 3;  // 0 or 2
    unsigned short* base = hT + (size_t)b * HH * 131072 + s * 2048;
#pragma unroll
    for (int it2 = 0; it2 < 2; ++it2) {
        const int k2 = it2 * 256 + t;
        const int hh = (k2 >> 7) & 3, ft2 = (k2 >> 5) & 3, l16 = (k2 >> 1) & 15, g = k2 & 1;
        const int col = hh * 64 + ft2 * 16 + l16;
        unsigned v[4];
#pragma unroll
        for (int p = 0; p < 4; ++p) {
            const unsigned lo = sm[(g * 8 + 2 * p) * 256 + col];
            const unsigned hi = sm[(g * 8 + 2 * p + 1) * 256 + col];
            v[p] = lo | (hi << 16);
        }
        uint4 pkt; pkt.x = v[0]; pkt.y = v[1]; pkt.z = v[2]; pkt.w = v[3];
        *(uint4*)(base + (size_t)hh * 131072 + ft2 * 512 + (qbase + g) * 128 + l16 * 8) = pkt;
    }
}

// ---------------------------------------------------------------------------
// K2: MFMA out kernel with FUSED softmax AND FUSED alpha write.
// XCD-swizzled (b = blk&7).  Phase A: psum-only pass -> rl (+rlArr for tail).
// Phase B: q = exp(s)*rl -> bf16 MFMA (pre-normalized acc) + q staged in a
// double-buffered LDS tile ps[2][16 i][4 h][68 jl], streamed to alpha as
// dense 256B-per-row float4 stores.
// R10 LESSON: __syncthreads() drains vmcnt(0) -> every alpha store retired
// before the next jt's MFMA (32 serial drains; fusion was SLOWER than split).
// Fix: in-loop barrier = lgkmcnt(0)-only + raw s_barrier + sched_barrier(0)
// (rule #18 fence) -- LDS visibility preserved, global stores stay in
// flight under subsequent compute.  One full __syncthreads at the end.
// jt=31 store CLAMPED to j < NN (R9 bug).  RACE SAFETY: blocks (b==0,
// it<18) skip alpha stores (hT/adjb scratch rows); k_alpha_tail fills them.
// ---------------------------------------------------------------------------
__global__ __launch_bounds__(256) void k_out_mfma6(const u64* __restrict__ adjb,
                                                   const unsigned short* __restrict__ hT,
                                                   const float* __restrict__ e_src,
                                                   const float* __restrict__ e_dst,
                                                   float* __restrict__ rlArr,
                                                   float* __restrict__ out,
                                                   float* __restrict__ alpha) {
    __shared__ __align__(16) float ps[2][16][HH][68];  // 34.8 KB
    const int blk = blockIdx.x;  // [0, 1000)
    const int b = blk & 7;       // XCD-aligned (1000 = 8 x 125)
    const int it = blk >> 3;
    const int i0 = it * 16;
    const int t = threadIdx.x;
    const int h = t >> 6, lane = t & 63;
    const int l16 = lane & 15, quad = lane >> 4;
    const int i = i0 + l16;  // < 2000 always
    const int bh = b * HH + h;
    const float es = e_src[bh * NN + i];
    const float* ed = e_dst + bh * NN;
    const u64* ab = adjb + (size_t)i * 32;
    const unsigned short* hbase = hT + (size_t)bh * 131072 + (size_t)lane * 8;

    // ---- Phase A: denominator (pad bits mask the j>=2000 overread) ----
    float psum = 0.f;
#pragma unroll 2
    for (int jt = 0; jt < 32; ++jt) {
        const u64 bits = ab[jt];
        const unsigned m0 = ((unsigned)(bits >> (quad * 8))) & 0xffu;
        const unsigned m1 = ((unsigned)(bits >> 32) >> (quad * 8)) & 0xffu;
        const float* ep = ed + jt * 64 + quad * 8;
        const float4 ea0 = *(const float4*)(ep);
        const float4 ea1 = *(const float4*)(ep + 4);
        const float4 eb0 = *(const float4*)(ep + 32);
        const float4 eb1 = *(const float4*)(ep + 36);
        const float ev0[8] = {ea0.x, ea0.y, ea0.z, ea0.w, ea1.x, ea1.y, ea1.z, ea1.w};
        const float ev1[8] = {eb0.x, eb0.y, eb0.z, eb0.w, eb1.x, eb1.y, eb1.z, eb1.w};
#pragma unroll
        for (int e = 0; e < 8; ++e) {
            float s0 = es + ev0[e]; s0 = s0 > 0.f ? s0 : 0.2f * s0;
            float s1 = es + ev1[e]; s1 = s1 > 0.f ? s1 : 0.2f * s1;
            psum += ((m0 >> e) & 1u) ? __expf(s0) : 0.f;
            psum += ((m1 >> e) & 1u) ? __expf(s1) : 0.f;
        }
    }
    psum += __shfl_xor(psum, 16);
    psum += __shfl_xor(psum, 32);
    const float rl = 1.f / psum;
    if (quad == 0) rlArr[bh * NN + i] = rl;

    // ---- Phase B: MFMA + alpha stream ----
    f32x4 acc[4];
#pragma unroll
    for (int ft = 0; ft < 4; ++ft) {
        acc[ft][0] = 0.f; acc[ft][1] = 0.f; acc[ft][2] = 0.f; acc[ft][3] = 0.f;
    }
    const bool wr = (b > 0) || (it >= 18);   // skip rows overlapping hT/adjb scratch
    const int ii = t >> 4, g = t & 15;
    float* arowbase = alpha + ((size_t)b * NN + i0 + ii) * (NN * HH);
    int buf = 0;
    for (int jt = 0; jt < 32; ++jt) {
        const u64 bits = ab[jt];
        const unsigned m0 = ((unsigned)(bits >> (quad * 8))) & 0xffu;
        const unsigned m1 = ((unsigned)(bits >> 32) >> (quad * 8)) & 0xffu;
        const float* ep = ed + jt * 64 + quad * 8;
        const float4 ea0 = *(const float4*)(ep);
        const float4 ea1 = *(const float4*)(ep + 4);
        const float4 eb0 = *(const float4*)(ep + 32);
        const float4 eb1 = *(const float4*)(ep + 36);
        const float ev0[8] = {ea0.x, ea0.y, ea0.z, ea0.w, ea1.x, ea1.y, ea1.z, ea1.w};
        const float ev1[8] = {eb0.x, eb0.y, eb0.z, eb0.w, eb1.x, eb1.y, eb1.z, eb1.w};
        const unsigned short* hp0 = hbase + (size_t)jt * 4096;
        {   // kk = 0
            f32x4 q0, q1;
            bf16x8 bfr;
#pragma unroll
            for (int e = 0; e < 8; ++e) {
                float s = es + ev0[e];
                s = s > 0.f ? s : 0.2f * s;
                const float q = (((m0 >> e) & 1u) ? __expf(s) : 0.f) * rl;
                bfr[e] = (short)f2bf(q);
                if (e < 4) q0[e] = q; else q1[e - 4] = q;
            }
            *(f32x4*)(&ps[buf][l16][h][quad * 8]) = q0;
            *(f32x4*)(&ps[buf][l16][h][quad * 8 + 4]) = q1;
#pragma unroll
            for (int ft = 0; ft < 4; ++ft) {
                const bf16x8 af = *(const bf16x8*)(hp0 + ft * 512);
                acc[ft] = __builtin_amdgcn_mfma_f32_16x16x32_bf16(af, bfr, acc[ft], 0, 0, 0);
            }
        }
        {   // kk = 1
            f32x4 q0, q1;
            bf16x8 bfr;
#pragma unroll
            for (int e = 0; e < 8; ++e) {
                float s = es + ev1[e];
                s = s > 0.f ? s : 0.2f * s;
                const float q = (((m1 >> e) & 1u) ? __expf(s) : 0.f) * rl;
                bfr[e] = (short)f2bf(q);
                if (e < 4) q0[e] = q; else q1[e - 4] = q;
            }
            *(f32x4*)(&ps[buf][l16][h][32 + quad * 8]) = q0;
            *(f32x4*)(&ps[buf][l16][h][32 + quad * 8 + 4]) = q1;
#pragma unroll
            for (int ft = 0; ft < 4; ++ft) {
                const bf16x8 af = *(const bf16x8*)(hp0 + 2048 + ft * 512);
                acc[ft] = __builtin_amdgcn_mfma_f32_16x16x32_bf16(af, bfr, acc[ft], 0, 0, 0);
            }
        }
        // LDS-only barrier: ps[buf] visible to all waves; alpha stores from
        // previous iterations are NOT drained (the whole point of the fusion)
        asm volatile("s_waitcnt lgkmcnt(0)" ::: "memory");
        __builtin_amdgcn_s_barrier();
        __builtin_amdgcn_sched_barrier(0);
        if (wr) {
            float* arow = arowbase + (size_t)jt * 256;
            const int jlim = NN - jt * 64;  // 64 except jt=31 -> 16 (row end!)
#pragma unroll
            for (int c = 0; c < 4; ++c) {
                const int jl = c * 16 + g;        // lanes g -> contiguous 256B
                if (jl < jlim) {
                    float4 ov;
                    ov.x = ps[buf][ii][0][jl];
                    ov.y = ps[buf][ii][1][jl];
                    ov.z = ps[buf][ii][2][jl];
                    ov.w = ps[buf][ii][3][jl];
                    *(float4*)(arow + (size_t)jl * 4) = ov;
                }
            }
        }
        buf ^= 1;  // next jt writes the other buffer; its reads completed
                   // before THIS barrier, so jt+2's rewrite is safe
    }
    // ---- out epilogue: cross-head reduction (acc already normalized) ----
    __syncthreads();  // single full drain (incl. last alpha stores)
    float* red = (float*)ps;  // [16][68]
#pragma unroll
    for (int ph = 0; ph < HH; ++ph) {
        if (h == ph) {
            if (ph == 0) {
#pragma unroll
                for (int ft = 0; ft < 4; ++ft)
                    *(f32x4*)(&red[l16 * 68 + ft * 16 + quad * 4]) = acc[ft];
            } else {
#pragma unroll
                for (int ft = 0; ft < 4; ++ft) {
                    f32x4 cur = *(const f32x4*)(&red[l16 * 68 + ft * 16 + quad * 4]);
#pragma unroll
                    for (int r = 0; r < 4; ++r) cur[r] += acc[ft][r];
                    *(f32x4*)(&red[l16 * 68 + ft * 16 + quad * 4]) = cur;
                }
            }
        }
        __syncthreads();
    }
    const int f4 = (t & 15) * 4;
    const f32x4 v = *(const f32x4*)(&red[(t >> 4) * 68 + f4]);
    f32x4 o;
#pragma unroll
    for (int r = 0; r < 4; ++r) o[r] = 0.25f * v[r];
    *(f32x4*)(out + (size_t)(b * NN + i0 + (t >> 4)) * FO + f4) = o;
}

// ---------------------------------------------------------------------------
// K3 (LAST): alpha tail for b=0, i in [0,288) -- the rows whose alpha region
// held hT/adjb scratch.  Reads the ORIGINAL adj input (never overwritten;
// avoids R1's scratch-read race).  Runs after mfma6, so hT is dead.
// ---------------------------------------------------------------------------
__global__ __launch_bounds__(256) void k_alpha_tail(const int* __restrict__ adj,
                                                    const float* __restrict__ e_src,
                                                    const float* __restrict__ e_dst,
                                                    const float* __restrict__ rlArr,
                                                    float* __restrict__ alpha) {
    const int i = blockIdx.x;  // [0, 288), b = 0
    const int t = threadIdx.x;
    float ei[HH], rr[HH];
#pragma unroll
    for (int h = 0; h < HH; ++h) {
        ei[h] = e_src[h * NN + i];
        rr[h] = rlArr[h * NN + i];
    }
    const int* adjrow = adj + (size_t)i * NN;
    float* arow = alpha + (size_t)i * (NN * HH);
#pragma unroll
    for (int k = 0; k < 8; ++k) {
        const int j = k * 256 + t;
        if (j < NN) {
            const bool av = adjrow[j] != 0;
            float o[HH];
#pragma unroll
            for (int h = 0; h < HH; ++h) {
                float s = ei[h] + e_dst[h * NN + j];
                s = s > 0.f ? s : 0.2f * s;
                o[h] = av ? __expf(s) * rr[h] : 0.f;
            }
            float4 ov = {o[0], o[1], o[2], o[3]};
            *(float4*)(arow + (size_t)j * HH) = ov;
        }
    }
}

// ---------------------------------------------------------------------------
// Launch (3 kernels).  hT at the start of the alpha output region; mfma6
// writes alpha only for rows >= 288 (b=0) -- disjoint from hT/adjb scratch,
// so concurrent read/write is safe; tail fills [0,288) afterwards.
//   ws bytes: [0,256000) e_src | [256000,512000) e_dst | [512000,768000) rl
//             [768000,1280000) adjb (if ws_size >= 1280000)
// ---------------------------------------------------------------------------
extern "C" void kernel_launch(void* const* d_in, const int* in_sizes, int n_in,
                              void* d_out, int out_size, void* d_ws, size_t ws_size,
                              hipStream_t stream) {
    const float* x  = (const float*)d_in[0];
    const int* adj  = (const int*)d_in[1];
    const float* W  = (const float*)d_in[2];
    const float* a  = (const float*)d_in[3];

    float* out = (float*)d_out;                         // B*N*FO floats
    float* alpha = out + (size_t)BB * NN * FO;          // B*N*N*H floats

    unsigned short* hT = (unsigned short*)alpha;        // 8.39 MB scratch (rows < 263)
    u64* adjb_scratch = (u64*)((char*)alpha + 8388608); // rows 262..279

    char* ws = (char*)d_ws;
    float* e_src = (float*)ws;
    float* e_dst = (float*)(ws + 256000);
    float* rlArr = (float*)(ws + 512000);
    const bool ws_has_adjb = ws_size >= 1280000;
    u64* adjb = ws_has_adjb ? (u64*)(ws + 768000) : adjb_scratch;

    k_gemm_all<<<2048, 256, 0, stream>>>(x, W, a, adj, e_src, e_dst, hT, adjb);
    k_out_mfma6<<<1000, 256, 0, stream>>>(adjb, hT, e_src, e_dst, rlArr, out, alpha);
    k_alpha_tail<<<288, 256, 0, stream>>>(adj, e_src, e_dst, rlArr, alpha);
}

// Round 12
// 631.737 us; speedup vs baseline: 1.0552x; 1.0426x over previous
//
#include <hip/hip_runtime.h>
#include <math.h>

#define BB 8
#define NN 2000
#define FIN 128
#define HH 4
#define FO 64
#define CC 256  // HH*FO

typedef short bf16x8 __attribute__((ext_vector_type(8)));
typedef float f32x4 __attribute__((ext_vector_type(4)));
typedef unsigned long long u64;

__device__ __forceinline__ unsigned short f2bf(float v) {
    union { float f; unsigned u; } x;
    x.f = v;
    unsigned r = x.u + 0x7fffu + ((x.u >> 16) & 1u);  // RNE
    return (unsigned short)(r >> 16);
}

// ---------------------------------------------------------------------------
// K1 (ALL-IN-ONE front end):
//   blocks [0,1000):    h = x@W -> e_src/e_dst (shuffle reduce) + hT
//                       (MFMA-fragment order) via 8KB LDS restage.
//   blocks [1000,2000): adjacency bitmask (grid-stride, 16 ballots/wave).
//   blocks [2000,2048): zero hT's j-pad (j in [2000,2048)) -- pad must be
//                       FINITE (MFMA 0*NaN would poison acc).
// ---------------------------------------------------------------------------
__global__ __launch_bounds__(256) void k_gemm_all(const float* __restrict__ x,
                                                  const float* __restrict__ W,
                                                  const float* __restrict__ a,
                                                  const int* __restrict__ adj,
                                                  float* __restrict__ e_src,
                                                  float* __restrict__ e_dst,
                                                  unsigned short* __restrict__ hT,
                                                  u64* __restrict__ adjb) {
    const int t = threadIdx.x;
    if (blockIdx.x >= 1000) {
        const int bx = blockIdx.x - 1000;
        if (bx < 1000) {
            const int lane = t & 63;
            for (int w = bx * 4 + (t >> 6); w < 64000; w += 4000) {
                const int i = w >> 5, wd = w & 31;
                const int j = wd * 64 + lane;
                int av = 0;
                if (j < NN) av = adj[(size_t)i * NN + j];
                const u64 mask = __ballot(av != 0);
                if (lane == 0) adjb[(size_t)i * 32 + wd] = mask;
            }
        } else {
            const int k = (bx - 1000) * 256 + t;  // [0, 12288)
            const int bh = k / 384;
            const int r = k - bh * 384;
            const int ft = r / 96;
            const int c = r - ft * 96;
            size_t off;
            if (c < 32) off = 62 * 2048 + ft * 512 + 256 + c * 8;
            else        off = 63 * 2048 + ft * 512 + (size_t)(c - 32) * 8;
            uint4 z; z.x = 0; z.y = 0; z.z = 0; z.w = 0;
            *(uint4*)(hT + (size_t)bh * 131072 + off) = z;
        }
        return;
    }
    __shared__ __align__(16) char smraw[8192];
    float* xs = (float*)smraw;                    // [16][128] during compute
    unsigned short* sm = (unsigned short*)smraw;  // [16][256] after re-barrier
    const int row0 = blockIdx.x * 16;
    for (int k = t; k < 16 * FIN; k += 256) xs[k] = x[row0 * FIN + k];
    __syncthreads();
    const int c = t;
    const int h = c >> 6, f = c & 63, lane = t & 63;
    float acc[16];
#pragma unroll
    for (int r = 0; r < 16; ++r) acc[r] = 0.f;
#pragma unroll 2
    for (int k = 0; k < FIN; k += 4) {
        const float w0 = W[(k + 0) * CC + c];
        const float w1 = W[(k + 1) * CC + c];
        const float w2 = W[(k + 2) * CC + c];
        const float w3 = W[(k + 3) * CC + c];
#pragma unroll
        for (int r = 0; r < 16; ++r) {
            const float4 xv = *(const float4*)(xs + r * FIN + k);
            acc[r] = fmaf(xv.x, w0, fmaf(xv.y, w1, fmaf(xv.z, w2, fmaf(xv.w, w3, acc[r]))));
        }
    }
    const int b = row0 / NN;
    const int n0 = row0 - b * NN;
    const float aS = a[h * 2 * FO + f];
    const float aD = a[h * 2 * FO + FO + f];
#pragma unroll
    for (int r = 0; r < 16; ++r) {
        float p1 = acc[r] * aS;
        float p2 = acc[r] * aD;
#pragma unroll
        for (int off = 32; off > 0; off >>= 1) {
            p1 += __shfl_xor(p1, off);
            p2 += __shfl_xor(p2, off);
        }
        if (lane == 0) {
            e_src[(b * HH + h) * NN + n0 + r] = p1;
            e_dst[(b * HH + h) * NN + n0 + r] = p2;
        }
    }
    __syncthreads();  // everyone done reading xs
#pragma unroll
    for (int r = 0; r < 16; ++r) sm[r * 256 + c] = f2bf(acc[r]);
    __syncthreads();
    const int s = n0 >> 5;
    const int qbase = (n0 >> 3) & 3;  // 0 or 2
    unsigned short* base = hT + (size_t)b * HH * 131072 + s * 2048;
#pragma unroll
    for (int it2 = 0; it2 < 2; ++it2) {
        const int k2 = it2 * 256 + t;
        const int hh = (k2 >> 7) & 3, ft2 = (k2 >> 5) & 3, l16 = (k2 >> 1) & 15, g = k2 & 1;
        const int col = hh * 64 + ft2 * 16 + l16;
        unsigned v[4];
#pragma unroll
        for (int p = 0; p < 4; ++p) {
            const unsigned lo = sm[(g * 8 + 2 * p) * 256 + col];
            const unsigned hi = sm[(g * 8 + 2 * p + 1) * 256 + col];
            v[p] = lo | (hi << 16);
        }
        uint4 pkt; pkt.x = v[0]; pkt.y = v[1]; pkt.z = v[2]; pkt.w = v[3];
        *(uint4*)(base + (size_t)hh * 131072 + ft2 * 512 + (qbase + g) * 128 + l16 * 8) = pkt;
    }
}

// ---------------------------------------------------------------------------
// K2: MFMA out kernel (R8 structure -- the measured-best).  ONE pass:
// unnormalized p = exp(s) feeds both the MFMA B-fragment and an inline psum;
// acc is scaled by rl = 1/psum afterwards (R10/R11's two-pass fused-alpha
// variant was 17-25 us SLOWER: 2x exp work + store stream robbed of TLP).
// XCD-swizzled (b = blk&7, 1000 = 8 x 125).  e_dst staged in LDS.
// ---------------------------------------------------------------------------
__global__ __launch_bounds__(256) void k_out_mfma5(const u64* __restrict__ adjb,
                                                   const unsigned short* __restrict__ hT,
                                                   const float* __restrict__ e_src,
                                                   const float* __restrict__ e_dst,
                                                   float* __restrict__ rlArr,
                                                   float* __restrict__ out) {
    __shared__ __align__(16) float eds[HH][2048];  // 32 KB; later reused as red[16][68]
    const int blk = blockIdx.x;  // [0, 1000)
    const int b = blk & 7;       // XCD-aligned
    const int it = blk >> 3;
    const int i0 = it * 16;
    const int t = threadIdx.x;
    const int h = t >> 6, lane = t & 63;
    const int l16 = lane & 15, quad = lane >> 4;
    // stage e_dst for all 4 heads (float4, coalesced; pad zeroed)
    for (int idx = t; idx < 2048; idx += 256) {
        const int h2 = idx >> 9, j4 = (idx & 511) * 4;
        float4 v = {0.f, 0.f, 0.f, 0.f};
        if (j4 < NN) v = *(const float4*)(e_dst + (b * HH + h2) * NN + j4);
        *(float4*)(&eds[h2][j4]) = v;
    }
    __syncthreads();
    const int i = i0 + l16;  // < 2000 always
    const int bh = b * HH + h;
    const float es = e_src[bh * NN + i];
    const u64* ab = adjb + (size_t)i * 32;
    const unsigned short* hbase = hT + (size_t)bh * 131072 + (size_t)lane * 8;

    f32x4 acc[4];
#pragma unroll
    for (int ft = 0; ft < 4; ++ft) {
        acc[ft][0] = 0.f; acc[ft][1] = 0.f; acc[ft][2] = 0.f; acc[ft][3] = 0.f;
    }
    float psum = 0.f;

#pragma unroll 2
    for (int jt = 0; jt < 32; ++jt) {
        const u64 bits = ab[jt];
        const unsigned m0 = ((unsigned)(bits >> (quad * 8))) & 0xffu;
        const unsigned m1 = ((unsigned)(bits >> 32) >> (quad * 8)) & 0xffu;
        const float* ep = &eds[h][jt * 64 + quad * 8];
        const f32x4 ea0 = *(const f32x4*)(ep);
        const f32x4 ea1 = *(const f32x4*)(ep + 4);
        const f32x4 eb0 = *(const f32x4*)(ep + 32);
        const f32x4 eb1 = *(const f32x4*)(ep + 36);
        const unsigned short* hp0 = hbase + (size_t)jt * 4096;

        {   // kk = 0
            const float ev[8] = {ea0[0], ea0[1], ea0[2], ea0[3], ea1[0], ea1[1], ea1[2], ea1[3]};
            bf16x8 bfr;
#pragma unroll
            for (int e = 0; e < 8; ++e) {
                float s = es + ev[e];
                s = s > 0.f ? s : 0.2f * s;
                float p = ((m0 >> e) & 1u) ? __expf(s) : 0.f;
                psum += p;
                bfr[e] = (short)f2bf(p);
            }
#pragma unroll
            for (int ft = 0; ft < 4; ++ft) {
                const bf16x8 af = *(const bf16x8*)(hp0 + ft * 512);
                acc[ft] = __builtin_amdgcn_mfma_f32_16x16x32_bf16(af, bfr, acc[ft], 0, 0, 0);
            }
        }
        {   // kk = 1
            const float ev[8] = {eb0[0], eb0[1], eb0[2], eb0[3], eb1[0], eb1[1], eb1[2], eb1[3]};
            bf16x8 bfr;
#pragma unroll
            for (int e = 0; e < 8; ++e) {
                float s = es + ev[e];
                s = s > 0.f ? s : 0.2f * s;
                float p = ((m1 >> e) & 1u) ? __expf(s) : 0.f;
                psum += p;
                bfr[e] = (short)f2bf(p);
            }
#pragma unroll
            for (int ft = 0; ft < 4; ++ft) {
                const bf16x8 af = *(const bf16x8*)(hp0 + 2048 + ft * 512);
                acc[ft] = __builtin_amdgcn_mfma_f32_16x16x32_bf16(af, bfr, acc[ft], 0, 0, 0);
            }
        }
    }
    // l for row i = sum over the 4 quads of this lane-column
    psum += __shfl_xor(psum, 16);
    psum += __shfl_xor(psum, 32);
    const float rl = 1.f / psum;
#pragma unroll
    for (int ft = 0; ft < 4; ++ft)
#pragma unroll
        for (int r = 0; r < 4; ++r) acc[ft][r] *= rl;
    if (quad == 0) rlArr[bh * NN + i] = rl;

    // cross-head reduction: reuse eds as red[16][68]
    __syncthreads();  // all waves done with eds
    float* red = (float*)eds;
#pragma unroll
    for (int ph = 0; ph < HH; ++ph) {
        if (h == ph) {
            if (ph == 0) {
#pragma unroll
                for (int ft = 0; ft < 4; ++ft)
                    *(f32x4*)(&red[l16 * 68 + ft * 16 + quad * 4]) = acc[ft];
            } else {
#pragma unroll
                for (int ft = 0; ft < 4; ++ft) {
                    f32x4 cur = *(const f32x4*)(&red[l16 * 68 + ft * 16 + quad * 4]);
#pragma unroll
                    for (int r = 0; r < 4; ++r) cur[r] += acc[ft][r];
                    *(f32x4*)(&red[l16 * 68 + ft * 16 + quad * 4]) = cur;
                }
            }
        }
        __syncthreads();
    }
    const int ii = t >> 4, f4 = (t & 15) * 4;
    const f32x4 v = *(const f32x4*)(&red[ii * 68 + f4]);
    f32x4 o;
#pragma unroll
    for (int r = 0; r < 4; ++r) o[r] = 0.25f * v[r];
    *(f32x4*)(out + (size_t)(b * NN + i0 + ii) * FO + f4) = o;
}

// ---------------------------------------------------------------------------
// K3 (LAST): alpha write, DENSE-store layout: lane t writes j = k*256+t ->
// each store instruction covers 4 KB contiguous.  16000 free-running blocks
// (max TLP for the 512 MB write-bound stream -- why this beats fusing the
// store into the MFMA kernel).  Runs last: hT scratch in alpha is dead.
// ---------------------------------------------------------------------------
__global__ __launch_bounds__(256) void k_alpha_bits(const u64* __restrict__ adjb,
                                                    const float* __restrict__ e_src,
                                                    const float* __restrict__ e_dst,
                                                    const float* __restrict__ rlArr,
                                                    float* __restrict__ alpha) {
    const int bi = blockIdx.x;
    const int b = bi / NN, i = bi - b * NN;
    const int t = threadIdx.x;
    float ei[HH], rr[HH];
#pragma unroll
    for (int h = 0; h < HH; ++h) {
        ei[h] = e_src[(b * HH + h) * NN + i];
        rr[h] = rlArr[(b * HH + h) * NN + i];
    }
    const float* ed = e_dst + b * HH * NN;
    const u64* ab = adjb + (size_t)i * 32;
    float* arow = alpha + (size_t)(b * NN + i) * (NN * HH);
#pragma unroll
    for (int k = 0; k < 8; ++k) {
        const int j = k * 256 + t;
        if (j < NN) {
            const u64 wbits = ab[j >> 6];  // wave-uniform
            const bool av = (wbits >> (j & 63)) & 1ull;
            float o[HH];
#pragma unroll
            for (int h = 0; h < HH; ++h) {
                float s = ei[h] + ed[h * NN + j];
                s = s > 0.f ? s : 0.2f * s;
                o[h] = av ? __expf(s) * rr[h] : 0.f;
            }
            float4 ov = {o[0], o[1], o[2], o[3]};
            *(float4*)(arow + (size_t)j * HH) = ov;
        }
    }
}

// Fallback if d_ws can't hold adjb (adjb then lives in alpha scratch, which
// this kernel overwrites -> must read the ORIGINAL adj input; R1's lesson).
__global__ __launch_bounds__(256) void k_alpha_adj(const int* __restrict__ adj,
                                                   const float* __restrict__ e_src,
                                                   const float* __restrict__ e_dst,
                                                   const float* __restrict__ rlArr,
                                                   float* __restrict__ alpha) {
    const int bi = blockIdx.x;
    const int b = bi / NN, i = bi - b * NN;
    const int t = threadIdx.x;
    float ei[HH], rr[HH];
#pragma unroll
    for (int h = 0; h < HH; ++h) {
        ei[h] = e_src[(b * HH + h) * NN + i];
        rr[h] = rlArr[(b * HH + h) * NN + i];
    }
    const float* ed = e_dst + b * HH * NN;
    const int* adjrow = adj + (size_t)i * NN;
    float* arow = alpha + (size_t)(b * NN + i) * (NN * HH);
#pragma unroll
    for (int k = 0; k < 8; ++k) {
        const int j = k * 256 + t;
        if (j < NN) {
            const bool av = adjrow[j] != 0;
            float o[HH];
#pragma unroll
            for (int h = 0; h < HH; ++h) {
                float s = ei[h] + ed[h * NN + j];
                s = s > 0.f ? s : 0.2f * s;
                o[h] = av ? __expf(s) * rr[h] : 0.f;
            }
            float4 ov = {o[0], o[1], o[2], o[3]};
            *(float4*)(arow + (size_t)j * HH) = ov;
        }
    }
}

// ---------------------------------------------------------------------------
// Launch (3 kernels).  hT at the start of the alpha output region (dead
// until k_alpha, which runs last).  adjb in d_ws when it fits.
//   ws bytes: [0,256000) e_src | [256000,512000) e_dst | [512000,768000) rl
//             [768000,1280000) adjb (if ws_size >= 1280000)
// ---------------------------------------------------------------------------
extern "C" void kernel_launch(void* const* d_in, const int* in_sizes, int n_in,
                              void* d_out, int out_size, void* d_ws, size_t ws_size,
                              hipStream_t stream) {
    const float* x  = (const float*)d_in[0];
    const int* adj  = (const int*)d_in[1];
    const float* W  = (const float*)d_in[2];
    const float* a  = (const float*)d_in[3];

    float* out = (float*)d_out;                         // B*N*FO floats
    float* alpha = out + (size_t)BB * NN * FO;          // B*N*N*H floats

    unsigned short* hT = (unsigned short*)alpha;        // 8.39 MB scratch
    u64* adjb_scratch = (u64*)((char*)alpha + 8388608);

    char* ws = (char*)d_ws;
    float* e_src = (float*)ws;
    float* e_dst = (float*)(ws + 256000);
    float* rlArr = (float*)(ws + 512000);
    const bool ws_has_adjb = ws_size >= 1280000;
    u64* adjb = ws_has_adjb ? (u64*)(ws + 768000) : adjb_scratch;

    k_gemm_all<<<2048, 256, 0, stream>>>(x, W, a, adj, e_src, e_dst, hT, adjb);
    k_out_mfma5<<<1000, 256, 0, stream>>>(adjb, hT, e_src, e_dst, rlArr, out);
    if (ws_has_adjb)
        k_alpha_bits<<<16000, 256, 0, stream>>>(adjb, e_src, e_dst, rlArr, alpha);
    else
        k_alpha_adj<<<16000, 256, 0, stream>>>(adj, e_src, e_dst, rlArr, alpha);
}